// Round 7
// baseline (555.511 us; speedup 1.0000x reference)
//
#include <hip/hip_runtime.h>
#include <cmath>

#define Hdim 512
#define Udim 32
#define Bdim 32
#define Tdim 2048
#define RM   64    // rows per block in K1 (4 waves x 16-row MFMA tiles)
#define KC   32    // k-chunk = one MFMA K

typedef __attribute__((ext_vector_type(8))) short bf16x8;
typedef __attribute__((ext_vector_type(4))) float f32x4;

// round-to-nearest-even f32 -> bf16 (bits)
__device__ __forceinline__ unsigned short f2bf(float f) {
    unsigned int u = __float_as_uint(f);
    u += 0x7FFFu + ((u >> 16) & 1u);
    return (unsigned short)(u >> 16);
}
__device__ __forceinline__ float bf2f(unsigned short h) {
    return __uint_as_float(((unsigned int)h) << 16);
}

// ---------------- Kernel 1: split-bf16 MFMA GEMMs + tanh + lambd combine -> delta [B*T, U] -----
// (unchanged from round 6: measured ~113us inferred, absmax 7.6e-6, total 435)
__global__ __launch_bounds__(256, 4) void k1_gemm_act(
    const float* __restrict__ x, const float* __restrict__ tin,
    const float* __restrict__ kx, const float* __restrict__ kt,
    const float* __restrict__ bx, const float* __restrict__ bt,
    const float* __restrict__ lambd, float* __restrict__ delta)
{
    __shared__ short axh[2048], axl[2048], ath[2048], atl[2048];   // 16 KB
    __shared__ short wxh[1024], wxl[1024], wth[1024], wtl[1024];   //  8 KB  (24 KB total)

    const int tid  = threadIdx.x;
    const int lane = tid & 63;
    const int wv   = tid >> 6;           // wave id 0..3 = row-tile
    const int row0 = blockIdx.x * RM;

    const int srow = tid >> 3;           // 0..31
    const int sk4  = tid & 7;            // float4 index in 32-k chunk
    const int aw_j0    = (sk4 & 1) * 4;
    const int aw_klane = 16 * (sk4 >> 1);
    const int su  = tid & 31;
    const int skq = tid >> 5;
    const int ww_idx = (su >> 4) * 512 + ((su & 15) + 16 * (skq >> 1)) * 8 + (skq & 1) * 4;

    const float4* xg = (const float4*)x;
    const float4* tg = (const float4*)tin;

    float4 px[2], pt[2];
    float  pwx[4], pwt[4];

    f32x4 accx[2], acct_[2];
#pragma unroll
    for (int ut = 0; ut < 2; ++ut) {
        accx[ut]  = (f32x4){0.f, 0.f, 0.f, 0.f};
        acct_[ut] = (f32x4){0.f, 0.f, 0.f, 0.f};
    }

    // prefetch chunk 0
#pragma unroll
    for (int l = 0; l < 2; ++l) {
        const size_t row = (size_t)(row0 + srow + 32 * l);
        px[l] = xg[row * (Hdim / 4) + sk4];
        pt[l] = tg[row * (Hdim / 4) + sk4];
    }
#pragma unroll
    for (int i = 0; i < 4; ++i) {
        pwx[i] = kx[(size_t)(skq * 4 + i) * Udim + su];
        pwt[i] = kt[(size_t)(skq * 4 + i) * Udim + su];
    }

#pragma unroll 1
    for (int c = 0; c < Hdim / KC; ++c) {
        __syncthreads();

#pragma unroll
        for (int l = 0; l < 2; ++l) {
            const int r   = srow + 32 * l;
            const int idx = (r >> 4) * 512 + ((r & 15) + aw_klane) * 8 + aw_j0;
            float4 v = px[l];
            unsigned short h0 = f2bf(v.x), h1 = f2bf(v.y), h2 = f2bf(v.z), h3 = f2bf(v.w);
            *(short4*)&axh[idx] = make_short4((short)h0, (short)h1, (short)h2, (short)h3);
            *(short4*)&axl[idx] = make_short4(
                (short)f2bf(v.x - bf2f(h0)), (short)f2bf(v.y - bf2f(h1)),
                (short)f2bf(v.z - bf2f(h2)), (short)f2bf(v.w - bf2f(h3)));
            v = pt[l];
            h0 = f2bf(v.x); h1 = f2bf(v.y); h2 = f2bf(v.z); h3 = f2bf(v.w);
            *(short4*)&ath[idx] = make_short4((short)h0, (short)h1, (short)h2, (short)h3);
            *(short4*)&atl[idx] = make_short4(
                (short)f2bf(v.x - bf2f(h0)), (short)f2bf(v.y - bf2f(h1)),
                (short)f2bf(v.z - bf2f(h2)), (short)f2bf(v.w - bf2f(h3)));
        }
        {
            unsigned short h0 = f2bf(pwx[0]), h1 = f2bf(pwx[1]), h2 = f2bf(pwx[2]), h3 = f2bf(pwx[3]);
            *(short4*)&wxh[ww_idx] = make_short4((short)h0, (short)h1, (short)h2, (short)h3);
            *(short4*)&wxl[ww_idx] = make_short4(
                (short)f2bf(pwx[0] - bf2f(h0)), (short)f2bf(pwx[1] - bf2f(h1)),
                (short)f2bf(pwx[2] - bf2f(h2)), (short)f2bf(pwx[3] - bf2f(h3)));
            h0 = f2bf(pwt[0]); h1 = f2bf(pwt[1]); h2 = f2bf(pwt[2]); h3 = f2bf(pwt[3]);
            *(short4*)&wth[ww_idx] = make_short4((short)h0, (short)h1, (short)h2, (short)h3);
            *(short4*)&wtl[ww_idx] = make_short4(
                (short)f2bf(pwt[0] - bf2f(h0)), (short)f2bf(pwt[1] - bf2f(h1)),
                (short)f2bf(pwt[2] - bf2f(h2)), (short)f2bf(pwt[3] - bf2f(h3)));
        }

        if (c + 1 < Hdim / KC) {
            const int cn = c + 1;
#pragma unroll
            for (int l = 0; l < 2; ++l) {
                const size_t row = (size_t)(row0 + srow + 32 * l);
                px[l] = xg[row * (Hdim / 4) + cn * (KC / 4) + sk4];
                pt[l] = tg[row * (Hdim / 4) + cn * (KC / 4) + sk4];
            }
#pragma unroll
            for (int i = 0; i < 4; ++i) {
                pwx[i] = kx[(size_t)(cn * KC + skq * 4 + i) * Udim + su];
                pwt[i] = kt[(size_t)(cn * KC + skq * 4 + i) * Udim + su];
            }
        }

        __syncthreads();

        const int ab = wv * 512 + lane * 8;
        bf16x8 Axh = *(const bf16x8*)&axh[ab];
        bf16x8 Axl = *(const bf16x8*)&axl[ab];
        bf16x8 Ath = *(const bf16x8*)&ath[ab];
        bf16x8 Atl = *(const bf16x8*)&atl[ab];
#pragma unroll
        for (int ut = 0; ut < 2; ++ut) {
            const int wb = ut * 512 + lane * 8;
            bf16x8 Bh = *(const bf16x8*)&wxh[wb];
            bf16x8 Bl = *(const bf16x8*)&wxl[wb];
            accx[ut] = __builtin_amdgcn_mfma_f32_16x16x32_bf16(Axh, Bh, accx[ut], 0, 0, 0);
            accx[ut] = __builtin_amdgcn_mfma_f32_16x16x32_bf16(Axh, Bl, accx[ut], 0, 0, 0);
            accx[ut] = __builtin_amdgcn_mfma_f32_16x16x32_bf16(Axl, Bh, accx[ut], 0, 0, 0);
            Bh = *(const bf16x8*)&wth[wb];
            Bl = *(const bf16x8*)&wtl[wb];
            acct_[ut] = __builtin_amdgcn_mfma_f32_16x16x32_bf16(Ath, Bh, acct_[ut], 0, 0, 0);
            acct_[ut] = __builtin_amdgcn_mfma_f32_16x16x32_bf16(Ath, Bl, acct_[ut], 0, 0, 0);
            acct_[ut] = __builtin_amdgcn_mfma_f32_16x16x32_bf16(Atl, Bh, acct_[ut], 0, 0, 0);
        }
    }

    const int crow = (lane >> 4) * 4;
    const int ccol = lane & 15;
    const float bx0 = bx[ccol],      bt0 = bt[ccol];
    const float bx1 = bx[16 + ccol], bt1 = bt[16 + ccol];
#pragma unroll
    for (int r = 0; r < 4; ++r) {
        const int grow = row0 + wv * 16 + crow + r;
        const float lam = lambd[grow & (Tdim - 1)];
        float g0  = tanhf(accx[0][r] + bx0);
        float be0 = tanhf(acct_[0][r] + bt0);
        float g1  = tanhf(accx[1][r] + bx1);
        float be1 = tanhf(acct_[1][r] + bt1);
        delta[(size_t)grow * Udim + ccol]      = lam * g0 + (1.0f - lam) * be0;
        delta[(size_t)grow * Udim + 16 + ccol] = lam * g1 + (1.0f - lam) * be1;
    }
}

// ---------------- Kernel 2: scores = delta @ kernel_a, softmax over T -> alpha -----------------
// No barriers in main loops (R2/R3-proven structure measured ~115-119 vs 134 LDS-staged).
// Grid 512 (32 b x 16 h-tiles of 32) = 2 independent blocks/CU (was 256 = 1/CU convoy).
// Half-wave <-> t-parity: 8 row-loads serve TWO rows per wave (VMEM instrs halved).
// 1-exp online update: rescale branch only on new max (exact same math as 2-exp form).
__global__ __launch_bounds__(512, 4) void k2_softmax(
    const float* __restrict__ delta, const float* __restrict__ ka_g,
    float* __restrict__ alpha)
{
    __shared__ float ms[16][32];
    __shared__ float ls[16][32];

    const int tid  = threadIdx.x;
    const int tx   = tid & 63;
    const int hx   = tx & 31;            // h within tile
    const int st   = (tid >> 6) * 2 + (tx >> 5);  // t-stream 0..15 (wave*2 + half)
    const int b    = blockIdx.x & 31;    // same-b blocks share delta via same-XCD L2
    const int ht   = blockIdx.x >> 5;    // 0..15
    const int h    = ht * 32 + hx;

    // kernel_a column for this lane's h (32 VGPRs)
    float ka[Udim];
#pragma unroll
    for (int u = 0; u < Udim; ++u) ka[u] = ka_g[u * Hdim + h];

    const float4* dsrc = (const float4*)(delta + (size_t)b * Tdim * Udim);

    // ---- pass 1: online (m, l); rows t = st + 16*i, i=0..127 ----
    float m = -1e30f, l = 0.f;
    {
        float4 q[8], nq[8];
        {
            const float4* p = dsrc + (size_t)st * (Udim / 4);
#pragma unroll
            for (int j = 0; j < 8; ++j) q[j] = p[j];
        }
#pragma unroll 2
        for (int i = 0; i < Tdim / 16; ++i) {
            const int tn = st + 16 * ((i + 1) & (Tdim / 16 - 1));
            const float4* np = dsrc + (size_t)tn * (Udim / 4);
#pragma unroll
            for (int j = 0; j < 8; ++j) nq[j] = np[j];

            float s0 = 0.f, s1 = 0.f, s2 = 0.f, s3 = 0.f;
#pragma unroll
            for (int j = 0; j < 8; ++j) {
                s0 = fmaf(q[j].x, ka[4 * j],     s0);
                s1 = fmaf(q[j].y, ka[4 * j + 1], s1);
                s2 = fmaf(q[j].z, ka[4 * j + 2], s2);
                s3 = fmaf(q[j].w, ka[4 * j + 3], s3);
            }
            const float s = (s0 + s1) + (s2 + s3);
            if (s > m) { l = l * __expf(m - s) + 1.0f; m = s; }
            else       { l += __expf(s - m); }
#pragma unroll
            for (int j = 0; j < 8; ++j) q[j] = nq[j];
        }
    }

    ms[st][hx] = m;
    ls[st][hx] = l;
    __syncthreads();
    float M = -1e30f;
#pragma unroll
    for (int w = 0; w < 16; ++w) M = fmaxf(M, ms[w][hx]);
    float L = 0.f;
#pragma unroll
    for (int w = 0; w < 16; ++w) L += ls[w][hx] * __expf(ms[w][hx] - M);
    const float rinv = 1.0f / L;

    // ---- pass 2: recompute scores, write alpha ----
    float* abase = alpha + (size_t)b * Tdim * Hdim + h;
    {
        float4 q[8], nq[8];
        {
            const float4* p = dsrc + (size_t)st * (Udim / 4);
#pragma unroll
            for (int j = 0; j < 8; ++j) q[j] = p[j];
        }
#pragma unroll 2
        for (int i = 0; i < Tdim / 16; ++i) {
            const int tn = st + 16 * ((i + 1) & (Tdim / 16 - 1));
            const float4* np = dsrc + (size_t)tn * (Udim / 4);
#pragma unroll
            for (int j = 0; j < 8; ++j) nq[j] = np[j];

            float s0 = 0.f, s1 = 0.f, s2 = 0.f, s3 = 0.f;
#pragma unroll
            for (int j = 0; j < 8; ++j) {
                s0 = fmaf(q[j].x, ka[4 * j],     s0);
                s1 = fmaf(q[j].y, ka[4 * j + 1], s1);
                s2 = fmaf(q[j].z, ka[4 * j + 2], s2);
                s3 = fmaf(q[j].w, ka[4 * j + 3], s3);
            }
            const float s = (s0 + s1) + (s2 + s3);
            const int t = st + 16 * i;
            abase[(size_t)t * Hdim] = __expf(s - M) * rinv;
#pragma unroll
            for (int j = 0; j < 8; ++j) q[j] = nq[j];
        }
    }
}

extern "C" void kernel_launch(void* const* d_in, const int* in_sizes, int n_in,
                              void* d_out, int out_size, void* d_ws, size_t ws_size,
                              hipStream_t stream) {
    const float* x     = (const float*)d_in[0];
    const float* tin   = (const float*)d_in[1];
    const float* kx    = (const float*)d_in[2];
    const float* kt    = (const float*)d_in[3];
    const float* ka    = (const float*)d_in[4];
    const float* bx    = (const float*)d_in[5];
    const float* bt    = (const float*)d_in[6];
    const float* lambd = (const float*)d_in[7];
    float* alpha = (float*)d_out;
    float* delta = (float*)d_ws;   // B*T*U*4 = 8 MB

    k1_gemm_act<<<(Bdim * Tdim) / RM, 256, 0, stream>>>(x, tin, kx, kt, bx, bt, lambd, delta);
    k2_softmax<<<512, 512, 0, stream>>>(delta, ka, alpha);
}